// Round 7
// baseline (201.203 us; speedup 1.0000x reference)
//
#include <hip/hip_runtime.h>
#include <stdint.h>

#define Hdim 112
#define Wdim 112
#define CIN  128
#define COUT 128
#define NB   32
#define HW   (Hdim*Wdim)   // 12544

// ws layout:
//   Wi8 : int8 [9][COUT][CIN]  @ 0        (147456 B)  weight signs as +-1
//   pkx : uint4[NB*HW]         @ 147456   (6.4 MB)    packed activation sign bits

typedef int v4i  __attribute__((ext_vector_type(4)));
typedef int v16i __attribute__((ext_vector_type(16)));

__global__ void pack_w_i8(const float* __restrict__ W, char* __restrict__ Wi8) {
    int t = blockIdx.x * blockDim.x + threadIdx.x;
    if (t >= COUT * 9) return;
    int co = t / 9, tap = t % 9;
    const float* wp = W + (size_t)co * CIN * 9 + tap;
    uint32_t* dst = (uint32_t*)(Wi8 + ((size_t)tap * COUT + co) * CIN);
    #pragma unroll
    for (int c4 = 0; c4 < 32; c4++) {
        uint32_t word = 0;
        #pragma unroll
        for (int j = 0; j < 4; j++) {
            uint32_t neg = __float_as_uint(wp[(size_t)(c4 * 4 + j) * 9]) >> 31;
            word |= (neg ? 0xFFu : 0x01u) << (8 * j);
        }
        dst[c4] = word;
    }
}

// each thread packs 4 consecutive pixels across all 128 channels (float4 loads)
__global__ __launch_bounds__(256) void pack_x_kernel(const float* __restrict__ x,
                                                     uint4* __restrict__ pkx) {
    int gid = blockIdx.x * blockDim.x + threadIdx.x;   // 0..100351
    int n = gid / (HW / 4);
    int p = (gid - n * (HW / 4)) * 4;
    const float* xp = x + (size_t)n * CIN * HW + p;
    uint32_t m[4][4] = {{0,0,0,0},{0,0,0,0},{0,0,0,0},{0,0,0,0}};
    #pragma unroll
    for (int c = 0; c < CIN; c++) {
        float4 v = *reinterpret_cast<const float4*>(xp + (size_t)c * HW);
        int q = c >> 5, s = c & 31;
        m[0][q] |= (__float_as_uint(v.x) >> 31) << s;
        m[1][q] |= (__float_as_uint(v.y) >> 31) << s;
        m[2][q] |= (__float_as_uint(v.z) >> 31) << s;
        m[3][q] |= (__float_as_uint(v.w) >> 31) << s;
    }
    uint4* op = pkx + (size_t)n * HW + p;
    #pragma unroll
    for (int j = 0; j < 4; j++)
        op[j] = make_uint4(m[j][0], m[j][1], m[j][2], m[j][3]);
}

// spread low 4 bits into 4 bytes: bit=0 -> 0x01 (+1), bit=1 -> 0xFF (-1)
__device__ __forceinline__ uint32_t expand4(uint32_t b) {
    uint32_t s = ((b & 0xFu) * 0x00204081u) & 0x01010101u;
    return 0x01010101u ^ (s * 0xFEu);
}

// implicit-GEMM binconv via i8 MFMA.
// Block: 128 co x (16w x 8h) pixels. Halo 10x18 pixels expanded from packed
// bits to i8 +-1 in LDS, layout [pixel][ci] with 16B-slot XOR swizzle
// (slot ^= pixel&7) to kill the stride-128B bank conflict.
// OOB pixels stage as TRUE i8 zeros (masked expansion) -> zero padding is
// exact, no border correction needed. (R6 bug: expand4 of bits=0 gave +1.)
__global__ __launch_bounds__(256, 4) void binconv_mfma(
    const uint4* __restrict__ pkx, const char* __restrict__ Wi8,
    const float* __restrict__ bias, float* __restrict__ out) {
    __shared__ uint4 halo4[10 * 18 * 8];          // 23040 B
    char* halo = (char*)halo4;

    int tid = threadIdx.x;
    int w0 = blockIdx.x * 16;
    int h0 = blockIdx.y * 8;
    int n  = blockIdx.z;

    // stage: one thread per halo pixel; expand 128 bits -> 128 i8 (swizzled)
    if (tid < 180) {
        int r = tid / 18, c = tid - r * 18;
        int h = h0 - 1 + r, w = w0 - 1 + c;
        bool valid = (h >= 0) && (h < Hdim) && (w >= 0) && (w < Wdim);
        uint32_t keep = valid ? 0xFFFFFFFFu : 0u;
        uint4 bits = make_uint4(0u, 0u, 0u, 0u);
        if (valid)
            bits = pkx[(size_t)n * HW + h * Wdim + w];
        uint32_t src[4] = {bits.x, bits.y, bits.z, bits.w};
        unsigned base = (unsigned)tid * 128;
        unsigned sw = ((unsigned)tid & 7u) << 4;
        #pragma unroll
        for (int s = 0; s < 8; s++) {             // slot s = ci 16s..16s+15
            uint32_t q = src[s >> 1] >> ((s & 1) * 16);
            uint4 ov;
            ov.x = expand4(q)       & keep;
            ov.y = expand4(q >> 4)  & keep;
            ov.z = expand4(q >> 8)  & keep;
            ov.w = expand4(q >> 12) & keep;
            *reinterpret_cast<uint4*>(&halo[base + (((unsigned)s << 4) ^ sw)]) = ov;
        }
    }
    __syncthreads();

    int wid = tid >> 6, l = tid & 63;
    int al = l & 31, ah = l >> 5;
    int cobase = (wid >> 1) << 6;     // 0 or 64
    int pxbase = (wid & 1) << 6;      // 0 or 64

    int p0 = pxbase + al;             // nt=0 pixel id in 16x8 tile
    int p1 = p0 + 32;                 // nt=1
    int pi0 = (p0 >> 4) * 18 + (p0 & 15);   // halo pixel index at tap (0,0)
    int pi1 = (p1 >> 4) * 18 + (p1 & 15);

    const char* wbase = Wi8 + (size_t)(cobase + al) * CIN + ah * 16;

    v16i acc00, acc01, acc10, acc11;
    #pragma unroll
    for (int i = 0; i < 16; i++) { acc00[i] = 0; acc01[i] = 0; acc10[i] = 0; acc11[i] = 0; }

    #pragma unroll
    for (int tap = 0; tap < 9; tap++) {
        int dy = tap / 3, dx = tap % 3;
        int q0 = pi0 + dy * 18 + dx;
        int q1 = pi1 + dy * 18 + dx;
        unsigned b0r = (unsigned)q0 * 128, b0s = ((unsigned)q0 & 7u) << 4;
        unsigned b1r = (unsigned)q1 * 128, b1s = ((unsigned)q1 & 7u) << 4;
        #pragma unroll
        for (int kk = 0; kk < 4; kk++) {
            v4i a0 = *reinterpret_cast<const v4i*>(wbase + (size_t)tap * COUT * CIN + kk * 32);
            v4i a1 = *reinterpret_cast<const v4i*>(wbase + (size_t)tap * COUT * CIN + 32 * CIN + kk * 32);
            unsigned soff = ((unsigned)(kk * 2 + ah)) << 4;
            v4i b0 = *reinterpret_cast<const v4i*>(&halo[b0r + (soff ^ b0s)]);
            v4i b1 = *reinterpret_cast<const v4i*>(&halo[b1r + (soff ^ b1s)]);
            acc00 = __builtin_amdgcn_mfma_i32_32x32x32_i8(a0, b0, acc00, 0, 0, 0);
            acc01 = __builtin_amdgcn_mfma_i32_32x32x32_i8(a0, b1, acc01, 0, 0, 0);
            acc10 = __builtin_amdgcn_mfma_i32_32x32x32_i8(a1, b0, acc10, 0, 0, 0);
            acc11 = __builtin_amdgcn_mfma_i32_32x32x32_i8(a1, b1, acc11, 0, 0, 0);
        }
    }

    // epilogue: C layout col=lane&31 (pixel), row=(reg&3)+8*(reg>>2)+4*ah (co)
    float* ob = out + (size_t)n * COUT * HW;
    int off0 = (h0 + (p0 >> 4)) * Wdim + w0 + (p0 & 15);
    int off1 = (h0 + (p1 >> 4)) * Wdim + w0 + (p1 & 15);
    #pragma unroll
    for (int reg = 0; reg < 16; reg++) {
        int co0 = cobase + (reg & 3) + ((reg >> 2) << 3) + (ah << 2);
        int co1 = co0 + 32;
        float bv0 = bias[co0];
        float bv1 = bias[co1];
        ob[(size_t)co0 * HW + off0] = (float)acc00[reg] + bv0;
        ob[(size_t)co0 * HW + off1] = (float)acc01[reg] + bv0;
        ob[(size_t)co1 * HW + off0] = (float)acc10[reg] + bv1;
        ob[(size_t)co1 * HW + off1] = (float)acc11[reg] + bv1;
    }
}

extern "C" void kernel_launch(void* const* d_in, const int* in_sizes, int n_in,
                              void* d_out, int out_size, void* d_ws, size_t ws_size,
                              hipStream_t stream) {
    const float* x = (const float*)d_in[0];
    const float* W = (const float*)d_in[1];
    const float* b = (const float*)d_in[2];
    float* out = (float*)d_out;
    char* ws = (char*)d_ws;
    char*  Wi8 = ws;
    uint4* pkx = (uint4*)(ws + 147456);

    pack_w_i8<<<dim3((COUT * 9 + 255) / 256), dim3(256), 0, stream>>>(W, Wi8);
    pack_x_kernel<<<dim3(NB * HW / 4 / 256), dim3(256), 0, stream>>>(x, pkx);
    binconv_mfma<<<dim3(7, 14, NB), dim3(256), 0, stream>>>(pkx, Wi8, b, out);
}

// Round 8
// 163.257 us; speedup vs baseline: 1.2324x; 1.2324x over previous
//
#include <hip/hip_runtime.h>
#include <stdint.h>

#define Hdim 112
#define Wdim 112
#define CIN  128
#define COUT 128
#define NB   32
#define HW   (Hdim*Wdim)   // 12544

// ws layout:
//   Wi8 : int8 [9][COUT][CIN]  @ 0        (147456 B)  weight signs as +-1
//   pkx : uint4[NB*HW]         @ 147456   (6.4 MB)    packed activation sign bits

typedef int v4i  __attribute__((ext_vector_type(4)));
typedef int v16i __attribute__((ext_vector_type(16)));

__global__ void pack_w_i8(const float* __restrict__ W, char* __restrict__ Wi8) {
    int t = blockIdx.x * blockDim.x + threadIdx.x;
    if (t >= COUT * 9) return;
    int co = t / 9, tap = t % 9;
    const float* wp = W + (size_t)co * CIN * 9 + tap;
    uint32_t* dst = (uint32_t*)(Wi8 + ((size_t)tap * COUT + co) * CIN);
    #pragma unroll
    for (int c4 = 0; c4 < 32; c4++) {
        uint32_t word = 0;
        #pragma unroll
        for (int j = 0; j < 4; j++) {
            uint32_t neg = __float_as_uint(wp[(size_t)(c4 * 4 + j) * 9]) >> 31;
            word |= (neg ? 0xFFu : 0x01u) << (8 * j);
        }
        dst[c4] = word;
    }
}

// each thread packs 4 consecutive pixels across all 128 channels (float4 loads)
__global__ __launch_bounds__(256) void pack_x_kernel(const float* __restrict__ x,
                                                     uint4* __restrict__ pkx) {
    int gid = blockIdx.x * blockDim.x + threadIdx.x;   // 0..100351
    int n = gid / (HW / 4);
    int p = (gid - n * (HW / 4)) * 4;
    const float* xp = x + (size_t)n * CIN * HW + p;
    uint32_t m[4][4] = {{0,0,0,0},{0,0,0,0},{0,0,0,0},{0,0,0,0}};
    #pragma unroll
    for (int c = 0; c < CIN; c++) {
        float4 v = *reinterpret_cast<const float4*>(xp + (size_t)c * HW);
        int q = c >> 5, s = c & 31;
        m[0][q] |= (__float_as_uint(v.x) >> 31) << s;
        m[1][q] |= (__float_as_uint(v.y) >> 31) << s;
        m[2][q] |= (__float_as_uint(v.z) >> 31) << s;
        m[3][q] |= (__float_as_uint(v.w) >> 31) << s;
    }
    uint4* op = pkx + (size_t)n * HW + p;
    #pragma unroll
    for (int j = 0; j < 4; j++)
        op[j] = make_uint4(m[j][0], m[j][1], m[j][2], m[j][3]);
}

// spread low 4 bits into 4 bytes: bit=0 -> 0x01 (+1), bit=1 -> 0xFF (-1)
__device__ __forceinline__ uint32_t expand4(uint32_t b) {
    uint32_t s = ((b & 0xFu) * 0x00204081u) & 0x01010101u;
    return 0x01010101u ^ (s * 0xFEu);
}

// implicit-GEMM binconv via i8 MFMA.
// Block: 128 co x (16w x 16h = 256 px). 4 waves, each 64co x 128px:
// 8 acc tiles (128 AGPR), next-tap A prefetched into VGPRs (needs the
// 256-reg budget from __launch_bounds__(256,2) — R7's (256,4) starved
// the allocator to 60 VGPR and serialized on L2 latency).
// Halo 18x18 px in LDS as [slot s][pixel q][16B] (slot = 16-ci group):
// addr = s*5184 + q*16 -> lane-consecutive 16B reads, conflict-free
// (R7's [pixel][128B] layout was inherently 4-way: row stride 128B means
// bank depends only on the slot, 3.6M conflict cycles).
// OOB pixels stage as true i8 zeros -> zero padding exact.
__global__ __launch_bounds__(256, 2) void binconv_mfma(
    const uint4* __restrict__ pkx, const char* __restrict__ Wi8,
    const float* __restrict__ bias, float* __restrict__ out) {
    __shared__ uint4 halo4[2592];           // 8 slots * 324 px * 16B = 41472 B
    char* halo = (char*)halo4;

    int tid = threadIdx.x;
    int w0 = blockIdx.x * 16;
    int h0 = blockIdx.y * 16;
    int n  = blockIdx.z;

    // stage 18x18 halo: expand 128 sign bits -> 128 i8 (+-1, 0 if OOB)
    for (int i = tid; i < 324; i += 256) {
        int r = i / 18, c = i - r * 18;
        int h = h0 - 1 + r, w = w0 - 1 + c;
        bool valid = (h >= 0) && (h < Hdim) && (w >= 0) && (w < Wdim);
        uint32_t keep = valid ? 0xFFFFFFFFu : 0u;
        uint4 bits = make_uint4(0u, 0u, 0u, 0u);
        if (valid) bits = pkx[(size_t)n * HW + h * Wdim + w];
        uint32_t src[4] = {bits.x, bits.y, bits.z, bits.w};
        #pragma unroll
        for (int s = 0; s < 8; s++) {       // slot s = ci 16s..16s+15
            uint32_t q = src[s >> 1] >> ((s & 1) * 16);
            uint4 ov;
            ov.x = expand4(q)       & keep;
            ov.y = expand4(q >> 4)  & keep;
            ov.z = expand4(q >> 8)  & keep;
            ov.w = expand4(q >> 12) & keep;
            *reinterpret_cast<uint4*>(&halo[s * 5184 + i * 16]) = ov;
        }
    }
    __syncthreads();

    int wid = tid >> 6, l = tid & 63;
    int al = l & 31, ah = l >> 5;
    int cobase = (wid & 1) * 64;            // wave's 64-co half
    int pxbase = (wid >> 1) * 128;          // wave's 128-px half (8 tile rows)

    // per-px-tile halo byte base at tap (0,0); ah's slot-half folded in
    int pib[4];
    #pragma unroll
    for (int pt = 0; pt < 4; pt++) {
        int p = pxbase + pt * 32 + al;
        pib[pt] = ((p >> 4) * 18 + (p & 15)) * 16 + ah * 5184;
    }

    const char* wA = Wi8 + (size_t)(cobase + al) * CIN + ah * 16;

    v16i acc[2][4];
    #pragma unroll
    for (int ct = 0; ct < 2; ct++)
        #pragma unroll
        for (int pt = 0; pt < 4; pt++)
            #pragma unroll
            for (int i = 0; i < 16; i++) acc[ct][pt][i] = 0;

    // A fragments for tap 0 (ct=0: co+0, ct=1: co+32)
    v4i A0[4], A1[4];
    #pragma unroll
    for (int kk = 0; kk < 4; kk++) {
        A0[kk] = *reinterpret_cast<const v4i*>(wA + kk * 32);
        A1[kk] = *reinterpret_cast<const v4i*>(wA + 32 * CIN + kk * 32);
    }

    #pragma unroll
    for (int tap = 0; tap < 9; tap++) {
        // prefetch next tap's A while this tap's MFMAs run
        v4i N0[4], N1[4];
        if (tap < 8) {
            const char* wt = wA + (size_t)(tap + 1) * COUT * CIN;
            #pragma unroll
            for (int kk = 0; kk < 4; kk++) {
                N0[kk] = *reinterpret_cast<const v4i*>(wt + kk * 32);
                N1[kk] = *reinterpret_cast<const v4i*>(wt + 32 * CIN + kk * 32);
            }
        }
        int doff = ((tap / 3) * 18 + (tap % 3)) * 16;
        #pragma unroll
        for (int kk = 0; kk < 4; kk++) {
            #pragma unroll
            for (int pt = 0; pt < 4; pt++) {
                v4i b = *reinterpret_cast<const v4i*>(&halo[kk * 2 * 5184 + pib[pt] + doff]);
                acc[0][pt] = __builtin_amdgcn_mfma_i32_32x32x32_i8(A0[kk], b, acc[0][pt], 0, 0, 0);
                acc[1][pt] = __builtin_amdgcn_mfma_i32_32x32x32_i8(A1[kk], b, acc[1][pt], 0, 0, 0);
            }
        }
        if (tap < 8) {
            #pragma unroll
            for (int kk = 0; kk < 4; kk++) { A0[kk] = N0[kk]; A1[kk] = N1[kk]; }
        }
    }

    // epilogue: C layout col=lane&31 (pixel), row=(reg&3)+8*(reg>>2)+4*ah (co)
    float* ob = out + (size_t)n * COUT * HW;
    #pragma unroll
    for (int ct = 0; ct < 2; ct++) {
        #pragma unroll
        for (int reg = 0; reg < 16; reg++) {
            int co = cobase + ct * 32 + (reg & 3) + ((reg >> 2) << 3) + (ah << 2);
            float bv = bias[co];
            #pragma unroll
            for (int pt = 0; pt < 4; pt++) {
                int p = pxbase + pt * 32 + al;
                int off = (h0 + (p >> 4)) * Wdim + w0 + (p & 15);
                ob[(size_t)co * HW + off] = (float)acc[ct][pt][reg] + bv;
            }
        }
    }
}

extern "C" void kernel_launch(void* const* d_in, const int* in_sizes, int n_in,
                              void* d_out, int out_size, void* d_ws, size_t ws_size,
                              hipStream_t stream) {
    const float* x = (const float*)d_in[0];
    const float* W = (const float*)d_in[1];
    const float* b = (const float*)d_in[2];
    float* out = (float*)d_out;
    char* ws = (char*)d_ws;
    char*  Wi8 = ws;
    uint4* pkx = (uint4*)(ws + 147456);

    pack_w_i8<<<dim3((COUT * 9 + 255) / 256), dim3(256), 0, stream>>>(W, Wi8);
    pack_x_kernel<<<dim3(NB * HW / 4 / 256), dim3(256), 0, stream>>>(x, pkx);
    binconv_mfma<<<dim3(7, 7, NB), dim3(256), 0, stream>>>(pkx, Wi8, b, out);
}